// Round 1
// baseline (332.069 us; speedup 1.0000x reference)
//
#include <hip/hip_runtime.h>

#define NUM_HEADS 32
#define NUM_KV_HEADS 8
#define HEAD_DIM 128
#define GQA 4
#define NUM_SEQS 8
#define BLKS_PER_SEQ 64
#define MEM_BLK 32
#define Q_LEN 64
#define SCALE 0.08838834764831845f

typedef __attribute__((ext_vector_type(4))) float f4;
typedef __attribute__((ext_vector_type(4))) float f32x4;
typedef __attribute__((ext_vector_type(8))) short short8;
typedef __attribute__((ext_vector_type(4))) unsigned int u32x4;

// round-to-nearest-even f32 -> bf16
__device__ __forceinline__ unsigned short f2bf(float f) {
  unsigned int u = __builtin_bit_cast(unsigned int, f);
  u += 0x7fffu + ((u >> 16) & 1u);
  return (unsigned short)(u >> 16);
}

// ---- LDS layout (bytes) ----
// K tiles (2 parities): [32 key][128 d] bf16, row 256B, swizzled
#define K_OFF   0
// V tiles (2 parities): transposed [128 d][32 key] bf16, row 64B, swizzled
#define V_OFF   16384
// P per-wave scratch: 8 waves x [16 rows][stride 80B]
#define P_OFF   32768
// merge m/l: 4 rg x [16 rows][2 f32]
#define ML_OFF  (32768 + 10240)
#define LDS_BYTES (32768 + 10240 + 512)
// merge O area reuses K/V region (4 rg x 8192B) after the loop.

__device__ __forceinline__ unsigned k_addr(int key, int d) {
  return (unsigned)(key * 256 + ((d * 2) ^ ((key & 7) << 4)));
}
__device__ __forceinline__ unsigned v_addr(int d, int key) {
  return (unsigned)(d * 64 + ((key * 2) ^ (((d >> 2) & 3) << 4)));
}

__global__ __launch_bounds__(512, 2)
void attn_paged_kernel(const float* __restrict__ q, const float* __restrict__ kn,
                       const float* __restrict__ vn, const float* __restrict__ kc,
                       const float* __restrict__ vc, const int* __restrict__ btab,
                       float* __restrict__ out)
{
  __shared__ __align__(16) char lds[LDS_BYTES];

  const int bid = blockIdx.x;
  const int sh  = bid & 63;      // bid = g*64 + s*8 + h  -> 4 GQA siblings share XCD (bid%8==h)
  const int g   = bid >> 6;
  const int s   = sh >> 3;
  const int h   = sh & 7;
  const int tid  = threadIdx.x;
  const int wave = tid >> 6, lane = tid & 63;
  const int rg  = wave & 3;      // q-row group (16 rows each)
  const int par = wave >> 2;     // KV tile parity handled by this wave
  const int lhi = lane >> 4, llo = lane & 15;

  // ---- Q fragments: A[i=llo][k-chunk lhi*8..] per 32-d chunk c ----
  short8 qf[4];
  {
    const float* qrow = q + (size_t)(s * Q_LEN + rg * 16 + llo) * 4096 + (h * GQA + g) * 128;
#pragma unroll
    for (int c = 0; c < 4; ++c) {
      const float* p = qrow + c * 32 + lhi * 8;
      f4 a = *(const f4*)p;
      f4 b = *(const f4*)(p + 4);
      short8 f;
      f[0] = (short)f2bf(a[0]); f[1] = (short)f2bf(a[1]);
      f[2] = (short)f2bf(a[2]); f[3] = (short)f2bf(a[3]);
      f[4] = (short)f2bf(b[0]); f[5] = (short)f2bf(b[1]);
      f[6] = (short)f2bf(b[2]); f[7] = (short)f2bf(b[3]);
      qf[c] = f;
    }
  }

  f32x4 of[8];
#pragma unroll
  for (int i = 0; i < 8; ++i) of[i] = (f32x4){0.f, 0.f, 0.f, 0.f};
  float m_run[4], l_run[4];
#pragma unroll
  for (int r = 0; r < 4; ++r) { m_run[r] = -1e30f; l_run[r] = 0.f; }

  // staging thread mapping
  const int ktk = tid >> 4;           // K tile row 0..31
  const int kc0 = (tid & 15) * 8;     // K col (8 f32)
  const int vcq = tid & 31;           // V d-quad (d = vcq*4+i)
  const int vtp = tid >> 5;           // V key pair (keys 2vtp, 2vtp+1)

  for (int it = 0; it < 33; ++it) {
    // ---- stage tiles 2it (even) and 2it+1 (odd): f32 -> bf16 into LDS ----
#pragma unroll
    for (int pp = 0; pp < 2; ++pp) {
      const int tile = 2 * it + pp;
      const float *ks, *vs0, *vs1;
      if (tile < BLKS_PER_SEQ) {
        const int pb = btab[s * BLKS_PER_SEQ + tile];
        const float* kb_ = kc + ((size_t)pb * MEM_BLK * NUM_KV_HEADS + h) * HEAD_DIM;
        const float* vb_ = vc + ((size_t)pb * MEM_BLK * NUM_KV_HEADS + h) * HEAD_DIM;
        ks  = kb_ + (size_t)ktk * (NUM_KV_HEADS * HEAD_DIM) + kc0;
        vs0 = vb_ + (size_t)(2 * vtp)     * (NUM_KV_HEADS * HEAD_DIM) + vcq * 4;
        vs1 = vb_ + (size_t)(2 * vtp + 1) * (NUM_KV_HEADS * HEAD_DIM) + vcq * 4;
      } else {
        const int base_t = (tile - BLKS_PER_SEQ) * MEM_BLK;
        ks  = kn + (size_t)(s * Q_LEN + base_t + ktk) * 1024 + h * HEAD_DIM + kc0;
        vs0 = vn + (size_t)(s * Q_LEN + base_t + 2 * vtp)     * 1024 + h * HEAD_DIM + vcq * 4;
        vs1 = vn + (size_t)(s * Q_LEN + base_t + 2 * vtp + 1) * 1024 + h * HEAD_DIM + vcq * 4;
      }
      f4 ka = *(const f4*)ks;  f4 kb2 = *(const f4*)(ks + 4);
      f4 va = *(const f4*)vs0; f4 vb2 = *(const f4*)vs1;
      u32x4 pk;
      pk[0] = (unsigned)f2bf(ka[0])  | ((unsigned)f2bf(ka[1])  << 16);
      pk[1] = (unsigned)f2bf(ka[2])  | ((unsigned)f2bf(ka[3])  << 16);
      pk[2] = (unsigned)f2bf(kb2[0]) | ((unsigned)f2bf(kb2[1]) << 16);
      pk[3] = (unsigned)f2bf(kb2[2]) | ((unsigned)f2bf(kb2[3]) << 16);
      *(u32x4*)(lds + K_OFF + pp * 8192 + k_addr(ktk, kc0)) = pk;
#pragma unroll
      for (int i = 0; i < 4; ++i) {   // V transposed: pack 2 keys per u32
        unsigned w = (unsigned)f2bf(va[i]) | ((unsigned)f2bf(vb2[i]) << 16);
        *(unsigned*)(lds + V_OFF + pp * 8192 + v_addr(vcq * 4 + i, 2 * vtp)) = w;
      }
    }
    __syncthreads();

    // ---- compute my parity's tile ----
    {
      const char* kb  = lds + K_OFF + par * 8192;
      const char* vbp = lds + V_OFF + par * 8192;
      f32x4 s0 = {0.f, 0.f, 0.f, 0.f}, s1 = {0.f, 0.f, 0.f, 0.f};
#pragma unroll
      for (int c = 0; c < 4; ++c) {
        short8 kf0 = *(const short8*)(kb + k_addr(llo,      c * 32 + lhi * 8));
        short8 kf1 = *(const short8*)(kb + k_addr(llo + 16, c * 32 + lhi * 8));
        s0 = __builtin_amdgcn_mfma_f32_16x16x32_bf16(qf[c], kf0, s0, 0, 0, 0);
        s1 = __builtin_amdgcn_mfma_f32_16x16x32_bf16(qf[c], kf1, s1, 0, 0, 0);
      }
      // online softmax: rows (lhi*4+r), cols llo / llo+16
      float p0[4], p1[4], corr[4], tred[4];
#pragma unroll
      for (int r = 0; r < 4; ++r) {
        s0[r] *= SCALE; s1[r] *= SCALE;
        tred[r] = fmaxf(s0[r], s1[r]);
      }
#pragma unroll
      for (int off = 1; off < 16; off <<= 1)
#pragma unroll
        for (int r = 0; r < 4; ++r) tred[r] = fmaxf(tred[r], __shfl_xor(tred[r], off, 64));
#pragma unroll
      for (int r = 0; r < 4; ++r) {
        float mnew = fmaxf(m_run[r], tred[r]);
        corr[r] = __expf(m_run[r] - mnew);
        p0[r] = __expf(s0[r] - mnew);
        p1[r] = __expf(s1[r] - mnew);
        m_run[r] = mnew;
        tred[r] = p0[r] + p1[r];
      }
#pragma unroll
      for (int off = 1; off < 16; off <<= 1)
#pragma unroll
        for (int r = 0; r < 4; ++r) tred[r] += __shfl_xor(tred[r], off, 64);
#pragma unroll
      for (int r = 0; r < 4; ++r) l_run[r] = l_run[r] * corr[r] + tred[r];
#pragma unroll
      for (int dc = 0; dc < 8; ++dc)
#pragma unroll
        for (int r = 0; r < 4; ++r) of[dc][r] *= corr[r];

      // P -> LDS (bf16, stride 80B) to re-layout into A-fragment
      char* pb_ = lds + P_OFF + wave * 1280;
#pragma unroll
      for (int r = 0; r < 4; ++r) {
        const int row = lhi * 4 + r;
        *(unsigned short*)(pb_ + row * 80 + llo * 2)        = f2bf(p0[r]);
        *(unsigned short*)(pb_ + row * 80 + (llo + 16) * 2) = f2bf(p1[r]);
      }
      short8 pa = *(const short8*)(pb_ + llo * 80 + lhi * 16);
#pragma unroll
      for (int dc = 0; dc < 8; ++dc) {
        short8 vf = *(const short8*)(vbp + v_addr(dc * 16 + llo, lhi * 8));
        of[dc] = __builtin_amdgcn_mfma_f32_16x16x32_bf16(pa, vf, of[dc], 0, 0, 0);
      }
    }
    __syncthreads();
  }

  // ---- merge the two context halves (parities) ----
  if (par == 1) {
    char* mo = lds + rg * 8192;   // reuse K/V region
#pragma unroll
    for (int dc = 0; dc < 8; ++dc)
#pragma unroll
      for (int r = 0; r < 4; ++r)
        *(float*)(mo + (lhi * 4 + r) * 512 + (dc * 16 + llo) * 4) = of[dc][r];
    if (llo == 0) {
      char* ml = lds + ML_OFF + rg * 128;
#pragma unroll
      for (int r = 0; r < 4; ++r) {
        *(float*)(ml + (lhi * 4 + r) * 8)     = m_run[r];
        *(float*)(ml + (lhi * 4 + r) * 8 + 4) = l_run[r];
      }
    }
  }
  __syncthreads();
  if (par == 0) {
    const char* mo = lds + rg * 8192;
    const char* ml = lds + ML_OFF + rg * 128;
    float ca[4], cb[4], inv[4];
#pragma unroll
    for (int r = 0; r < 4; ++r) {
      const float mb = *(const float*)(ml + (lhi * 4 + r) * 8);
      const float lb = *(const float*)(ml + (lhi * 4 + r) * 8 + 4);
      const float mf = fmaxf(m_run[r], mb);
      ca[r] = __expf(m_run[r] - mf);
      cb[r] = __expf(mb - mf);
      inv[r] = 1.f / (ca[r] * l_run[r] + cb[r] * lb);
    }
#pragma unroll
    for (int dc = 0; dc < 8; ++dc)
#pragma unroll
      for (int r = 0; r < 4; ++r) {
        const float ob = *(const float*)(mo + (lhi * 4 + r) * 512 + (dc * 16 + llo) * 4);
        const float val = (ca[r] * of[dc][r] + cb[r] * ob) * inv[r];
        out[(size_t)(s * Q_LEN + rg * 16 + lhi * 4 + r) * 4096
            + (size_t)((h * GQA + g) * 128 + dc * 16 + llo)] = val;
      }
  }
}

extern "C" void kernel_launch(void* const* d_in, const int* in_sizes, int n_in,
                              void* d_out, int out_size, void* d_ws, size_t ws_size,
                              hipStream_t stream) {
  (void)in_sizes; (void)n_in; (void)d_ws; (void)ws_size; (void)out_size;
  const float* q  = (const float*)d_in[0];
  const float* k  = (const float*)d_in[1];
  const float* v  = (const float*)d_in[2];
  const float* kc = (const float*)d_in[3];
  const float* vc = (const float*)d_in[4];
  const int* bt   = (const int*)d_in[5];
  float* out = (float*)d_out;
  attn_paged_kernel<<<dim3(256), dim3(512), 0, stream>>>(q, k, v, kc, vc, bt, out);
}

// Round 6
// 300.802 us; speedup vs baseline: 1.1039x; 1.1039x over previous
//
#include <hip/hip_runtime.h>

#define NUM_HEADS 32
#define NUM_KV_HEADS 8
#define HEAD_DIM 128
#define GQA 4
#define NUM_SEQS 8
#define BLKS_PER_SEQ 64
#define MEM_BLK 32
#define Q_LEN 64
#define SCALE 0.08838834764831845f
#define RLN2 1.4426950408889634f

typedef __attribute__((ext_vector_type(4))) float f4;
typedef __attribute__((ext_vector_type(4))) float f32x4;
typedef __attribute__((ext_vector_type(8))) short short8;
typedef __attribute__((ext_vector_type(4))) unsigned int u32x4;

// packed f32 pair -> bf16x2 (RNE), single instruction
__device__ __forceinline__ unsigned cvt_pk(float lo, float hi) {
  unsigned r;
  asm("v_cvt_pk_bf16_f32 %0, %1, %2" : "=v"(r) : "v"(lo), "v"(hi));
  return r;
}
// scalar f32 -> bf16 (RNE) for P writes
__device__ __forceinline__ unsigned short f2bf(float f) {
  unsigned int u = __builtin_bit_cast(unsigned int, f);
  u += 0x7fffu + ((u >> 16) & 1u);
  return (unsigned short)(u >> 16);
}

// ---- LDS layout (bytes) ----
#define K_OFF   0                 // 2 par x [32 key][128 d] bf16, swizzled (16 KB)
#define V_OFF   16384             // 2 par x [128 d][32 key] bf16 transposed, swizzled (16 KB)
#define P_OFF   32768             // 8 waves x [16 rows][stride 80B] (10 KB)
#define ML_OFF  43008             // 4 rg x [16 rows][2 f32]
#define BT_OFF  43520             // 64 x int block table
#define LDS_BYTES 43776

__device__ __forceinline__ unsigned k_addr(int key, int d) {
  return (unsigned)(key * 256 + ((d * 2) ^ ((key & 7) << 4)));
}
__device__ __forceinline__ unsigned v_addr(int d, int key) {
  return (unsigned)(d * 64 + ((key * 2) ^ (((d >> 2) & 3) << 4)));
}

__global__ __launch_bounds__(512, 2)
void attn_paged_kernel(const float* __restrict__ q, const float* __restrict__ kn,
                       const float* __restrict__ vn, const float* __restrict__ kc,
                       const float* __restrict__ vc, const int* __restrict__ btab,
                       float* __restrict__ out)
{
  __shared__ __align__(16) char lds[LDS_BYTES];

  const int bid = blockIdx.x;
  const int sh  = bid & 63;      // bid = g*64 + s*8 + h -> GQA siblings share XCD
  const int g   = bid >> 6;
  const int s   = sh >> 3;
  const int h   = sh & 7;
  const int tid  = threadIdx.x;
  const int wave = tid >> 6, lane = tid & 63;
  const int rg  = wave & 3;      // q-row group (16 rows)
  const int par = wave >> 2;     // KV tile parity
  const int lhi = lane >> 4, llo = lane & 15;

  // block table -> LDS (once)
  if (tid < 64) *(int*)(lds + BT_OFF + tid * 4) = btab[s * BLKS_PER_SEQ + tid];

  // ---- Q fragments, pre-scaled by SCALE/ln2 (exp2 domain) ----
  short8 qf[4];
  {
    const float qsc = SCALE * RLN2;
    const float* qrow = q + (size_t)(s * Q_LEN + rg * 16 + llo) * 4096 + (h * GQA + g) * 128;
#pragma unroll
    for (int c = 0; c < 4; ++c) {
      const float* p = qrow + c * 32 + lhi * 8;
      f4 a = *(const f4*)p;
      f4 b = *(const f4*)(p + 4);
      u32x4 w;
      w[0] = cvt_pk(a[0] * qsc, a[1] * qsc);
      w[1] = cvt_pk(a[2] * qsc, a[3] * qsc);
      w[2] = cvt_pk(b[0] * qsc, b[1] * qsc);
      w[3] = cvt_pk(b[2] * qsc, b[3] * qsc);
      qf[c] = __builtin_bit_cast(short8, w);
    }
  }

  f32x4 of[8];
#pragma unroll
  for (int i = 0; i < 8; ++i) of[i] = (f32x4){0.f, 0.f, 0.f, 0.f};
  float m_run[4], l_run[4];
#pragma unroll
  for (int r = 0; r < 4; ++r) { m_run[r] = -1e30f; l_run[r] = 0.f; }

  // staging thread mapping + invariant offsets
  const int ktk = tid >> 4;           // K tile row 0..31
  const int kc0 = (tid & 15) * 8;     // K col (8 f32)
  const int vcq = tid & 31;           // V d-quad
  const int vtp = tid >> 5;           // V key pair
  const size_t k_toff  = (size_t)ktk * 1024 + h * HEAD_DIM + kc0;
  const size_t v_toff0 = (size_t)(2 * vtp) * 1024 + h * HEAD_DIM + vcq * 4;
  char* kw  = lds + K_OFF + k_addr(ktk, kc0);
  char* vw0 = lds + V_OFF + v_addr(vcq * 4, 2 * vtp);   // +i*64 for quad elem i

  __syncthreads();  // block table visible

  // prefetch registers
  f4 rka[2], rkb[2], rva[2], rvb[2];

  auto issue_loads = [&](int it_next) {
#pragma unroll
    for (int pp = 0; pp < 2; ++pp) {
      const int tile = 2 * it_next + pp;
      const float *kb_, *vb_;
      if (tile < BLKS_PER_SEQ) {
        const int pb = *(const int*)(lds + BT_OFF + tile * 4);
        kb_ = kc + (size_t)pb * 32768;
        vb_ = vc + (size_t)pb * 32768;
      } else {
        const size_t row = (size_t)(s * Q_LEN + (tile - BLKS_PER_SEQ) * MEM_BLK) * 1024;
        kb_ = kn + row;
        vb_ = vn + row;
      }
      rka[pp] = *(const f4*)(kb_ + k_toff);
      rkb[pp] = *(const f4*)(kb_ + k_toff + 4);
      rva[pp] = *(const f4*)(vb_ + v_toff0);
      rvb[pp] = *(const f4*)(vb_ + v_toff0 + 1024);
    }
  };
  auto write_tiles = [&]() {
#pragma unroll
    for (int pp = 0; pp < 2; ++pp) {
      u32x4 w;
      w[0] = cvt_pk(rka[pp][0], rka[pp][1]);
      w[1] = cvt_pk(rka[pp][2], rka[pp][3]);
      w[2] = cvt_pk(rkb[pp][0], rkb[pp][1]);
      w[3] = cvt_pk(rkb[pp][2], rkb[pp][3]);
      *(u32x4*)(kw + pp * 8192) = w;
#pragma unroll
      for (int i = 0; i < 4; ++i)
        *(unsigned*)(vw0 + pp * 8192 + i * 64) = cvt_pk(rva[pp][i], rvb[pp][i]);
    }
  };

  // prologue: stage tile pair 0
  issue_loads(0);
  write_tiles();
  __syncthreads();

  for (int it = 0; it < 33; ++it) {
    if (it < 32) issue_loads(it + 1);   // loads fly during compute

    // ---- compute my parity's tile ----
    {
      const char* kb  = lds + K_OFF + par * 8192;
      const char* vbp = lds + V_OFF + par * 8192;
      f32x4 s0 = {0.f, 0.f, 0.f, 0.f}, s1 = {0.f, 0.f, 0.f, 0.f};
#pragma unroll
      for (int c = 0; c < 4; ++c) {
        short8 kf0 = *(const short8*)(kb + k_addr(llo,      c * 32 + lhi * 8));
        short8 kf1 = *(const short8*)(kb + k_addr(llo + 16, c * 32 + lhi * 8));
        s0 = __builtin_amdgcn_mfma_f32_16x16x32_bf16(qf[c], kf0, s0, 0, 0, 0);
        s1 = __builtin_amdgcn_mfma_f32_16x16x32_bf16(qf[c], kf1, s1, 0, 0, 0);
      }
      // online softmax in exp2 domain; rows lhi*4+r, cols llo / llo+16
      float p0[4], p1[4], tred[4];
#pragma unroll
      for (int r = 0; r < 4; ++r) tred[r] = fmaxf(s0[r], s1[r]);
#pragma unroll
      for (int off = 1; off < 16; off <<= 1)
#pragma unroll
        for (int r = 0; r < 4; ++r) tred[r] = fmaxf(tred[r], __shfl_xor(tred[r], off, 64));

      bool grow = (tred[0] > m_run[0]) | (tred[1] > m_run[1]) |
                  (tred[2] > m_run[2]) | (tred[3] > m_run[3]);
      const int resc = __any((int)grow);   // wave-uniform
      float corr[4];
      if (resc) {
#pragma unroll
        for (int r = 0; r < 4; ++r) {
          const float mnew = fmaxf(m_run[r], tred[r]);
          corr[r] = exp2f(m_run[r] - mnew);
          m_run[r] = mnew;
        }
      }
#pragma unroll
      for (int r = 0; r < 4; ++r) {
        p0[r] = exp2f(s0[r] - m_run[r]);
        p1[r] = exp2f(s1[r] - m_run[r]);
        tred[r] = p0[r] + p1[r];
      }
#pragma unroll
      for (int off = 1; off < 16; off <<= 1)
#pragma unroll
        for (int r = 0; r < 4; ++r) tred[r] += __shfl_xor(tred[r], off, 64);
      if (resc) {
#pragma unroll
        for (int r = 0; r < 4; ++r) l_run[r] = l_run[r] * corr[r] + tred[r];
#pragma unroll
        for (int dc = 0; dc < 8; ++dc)
#pragma unroll
          for (int r = 0; r < 4; ++r) of[dc][r] *= corr[r];
      } else {
#pragma unroll
        for (int r = 0; r < 4; ++r) l_run[r] += tred[r];
      }

      // P -> LDS (bf16, stride 80B) for A-fragment re-layout
      char* pb_ = lds + P_OFF + wave * 1280;
#pragma unroll
      for (int r = 0; r < 4; ++r) {
        const int row = lhi * 4 + r;
        *(unsigned short*)(pb_ + row * 80 + llo * 2)        = f2bf(p0[r]);
        *(unsigned short*)(pb_ + row * 80 + (llo + 16) * 2) = f2bf(p1[r]);
      }
      short8 pa = *(const short8*)(pb_ + llo * 80 + lhi * 16);
#pragma unroll
      for (int dc = 0; dc < 8; ++dc) {
        short8 vf = *(const short8*)(vbp + v_addr(dc * 16 + llo, lhi * 8));
        of[dc] = __builtin_amdgcn_mfma_f32_16x16x32_bf16(pa, vf, of[dc], 0, 0, 0);
      }
    }

    __syncthreads();                 // all reads of tile `it` done
    if (it < 32) write_tiles();      // loads landed during compute; convert+write
    __syncthreads();                 // writes visible for iter it+1
  }

  // ---- merge the two parity halves ----
  if (par == 1) {
    char* mo = lds + rg * 8192;   // reuse K/V region
#pragma unroll
    for (int dc = 0; dc < 8; ++dc)
#pragma unroll
      for (int r = 0; r < 4; ++r)
        *(float*)(mo + (lhi * 4 + r) * 512 + (dc * 16 + llo) * 4) = of[dc][r];
    if (llo == 0) {
      char* ml = lds + ML_OFF + rg * 128;
#pragma unroll
      for (int r = 0; r < 4; ++r) {
        *(float*)(ml + (lhi * 4 + r) * 8)     = m_run[r];
        *(float*)(ml + (lhi * 4 + r) * 8 + 4) = l_run[r];
      }
    }
  }
  __syncthreads();
  if (par == 0) {
    const char* mo = lds + rg * 8192;
    const char* ml = lds + ML_OFF + rg * 128;
    float ca[4], cb[4], inv[4];
#pragma unroll
    for (int r = 0; r < 4; ++r) {
      const float mb = *(const float*)(ml + (lhi * 4 + r) * 8);
      const float lb = *(const float*)(ml + (lhi * 4 + r) * 8 + 4);
      const float mf = fmaxf(m_run[r], mb);
      ca[r] = exp2f(m_run[r] - mf);
      cb[r] = exp2f(mb - mf);
      inv[r] = 1.f / (ca[r] * l_run[r] + cb[r] * lb);
    }
#pragma unroll
    for (int dc = 0; dc < 8; ++dc)
#pragma unroll
      for (int r = 0; r < 4; ++r) {
        const float ob = *(const float*)(mo + (lhi * 4 + r) * 512 + (dc * 16 + llo) * 4);
        const float val = (ca[r] * of[dc][r] + cb[r] * ob) * inv[r];
        out[(size_t)(s * Q_LEN + rg * 16 + lhi * 4 + r) * 4096
            + (size_t)((h * GQA + g) * 128 + dc * 16 + llo)] = val;
      }
  }
}

extern "C" void kernel_launch(void* const* d_in, const int* in_sizes, int n_in,
                              void* d_out, int out_size, void* d_ws, size_t ws_size,
                              hipStream_t stream) {
  (void)in_sizes; (void)n_in; (void)d_ws; (void)ws_size; (void)out_size;
  const float* q  = (const float*)d_in[0];
  const float* k  = (const float*)d_in[1];
  const float* v  = (const float*)d_in[2];
  const float* kc = (const float*)d_in[3];
  const float* vc = (const float*)d_in[4];
  const int* bt   = (const int*)d_in[5];
  float* out = (float*)d_out;
  attn_paged_kernel<<<dim3(256), dim3(512), 0, stream>>>(q, k, v, kc, vc, bt, out);
}